// Round 1
// baseline (676.924 us; speedup 1.0000x reference)
//
#include <hip/hip_runtime.h>
#include <stdint.h>

#define NTOK  262144
#define HD    256
#define BM    64
#define NBLK  (NTOK / BM)   // 4096

typedef unsigned short u16;
typedef __attribute__((ext_vector_type(8))) short bfrag;   // 8 bf16 (4 VGPRs)
typedef __attribute__((ext_vector_type(4))) float facc;    // MFMA C/D
typedef __attribute__((ext_vector_type(4))) float f32x4v;

// ---- ws layout (bytes) ----
#define WS_W1T   0          // bf16 [kc=4][c=256][u=8][8]          = 131072 B
#define WS_WET   131072     // bf16 [e=4][kc=4][c=256][u=8][8]     = 524288 B
#define WS_WCOMB 655360     // f32  [k=256][e=4]                   = 4096 B
#define WS_BCOMB 659456     // f32  [4]

static __device__ __forceinline__ u16 f2bf(float f) {  // fp32 -> bf16 RNE
  union { float f; uint32_t u; } v; v.f = f;
  uint32_t r = v.u + 0x7FFFu + ((v.u >> 16) & 1u);
  return (u16)(r >> 16);
}

static __device__ __forceinline__ void async16(void* lds, const void* g) {
  __builtin_amdgcn_global_load_lds(
      (const __attribute__((address_space(1))) uint32_t*)g,
      (__attribute__((address_space(3))) uint32_t*)lds, 16, 0, 0);
}

// ---------- prep 1: Wcomb = W1@Wg, bcomb = b1@Wg (fp64) ----------
__global__ __launch_bounds__(256)
void prep_comb(const float* __restrict__ W1, const float* __restrict__ b1,
               const float* __restrict__ Wg,
               float* __restrict__ wcomb, float* __restrict__ bcomb) {
  int t = blockIdx.x * 256 + threadIdx.x;
  if (t < 1024) {
    int k = t >> 2, e = t & 3;
    double acc = 0.0;
    for (int m = 0; m < 256; ++m)
      acc += (double)W1[k * 256 + m] * (double)Wg[m * 4 + e];
    wcomb[k * 4 + e] = (float)acc;
  } else if (t < 1028) {
    int e = t - 1024;
    double acc = 0.0;
    for (int m = 0; m < 256; ++m)
      acc += (double)b1[m] * (double)Wg[m * 4 + e];
    bcomb[e] = (float)acc;
  }
}

// ---------- prep 2: transpose+swizzle+bf16-cast W1, We ----------
// LDS slot (c*8 + u_phys) must hold W[k = kc*64 + (u_phys^(c&7))*8 + j][c],
// so that global_load_lds (linear, lane*16) lands the XOR-swizzled layout.
__global__ __launch_bounds__(256)
void prep_swz(const float* __restrict__ W1, const float* __restrict__ We,
              u16* __restrict__ w1t, u16* __restrict__ wet) {
  int t = blockIdx.x * 256 + threadIdx.x;
  if (t < 8192) {                       // W1: 4 chunks * 2048 slots
    int kc = t >> 11, rem = t & 2047;
    int c = rem >> 3, up = rem & 7;
    int u = up ^ (c & 7);
    int kb = kc * 64 + u * 8;
    bfrag tmp;
#pragma unroll
    for (int j = 0; j < 8; ++j) tmp[j] = (short)f2bf(W1[(size_t)(kb + j) * 256 + c]);
    *(bfrag*)(w1t + (size_t)t * 8) = tmp;
  } else if (t < 8192 + 32768) {        // We: 4 experts * 4 chunks * 2048 slots
    int s = t - 8192;
    int e = s >> 13, rem = s & 8191;
    int kc = rem >> 11, r2 = rem & 2047;
    int c = r2 >> 3, up = r2 & 7;
    int u = up ^ (c & 7);
    int kb = kc * 64 + u * 8;
    const float* Wep = We + (size_t)e * 65536;
    bfrag tmp;
#pragma unroll
    for (int j = 0; j < 8; ++j) tmp[j] = (short)f2bf(Wep[(size_t)(kb + j) * 256 + c]);
    *(bfrag*)(wet + (size_t)s * 8) = tmp;
  }
}

// ---------- fused MoE kernel ----------
__global__ __launch_bounds__(256, 2)
void moe_fused(const float* __restrict__ x,
               const u16* __restrict__ w1t, const u16* __restrict__ wet,
               const float* __restrict__ wcomb, const float* __restrict__ bcomb,
               const float* __restrict__ b1, const float* __restrict__ be,
               float* __restrict__ out) {
  __shared__ u16   hs[BM][264];          // h tile, bf16, +8 pad (33792 B)
  __shared__ u16   bstage[2048 * 8];     // B-slice staging (32768 B)
  __shared__ float b1s[256];
  __shared__ float bes[4][256];
  __shared__ float logits_s[64][4];
  __shared__ float gate_s[64];
  __shared__ int   pos_s[64];
  __shared__ int   eidx_s[64];
  __shared__ int   perm_s[64];
  __shared__ int   cnt_s[4];
  __shared__ int   base_s[5];

  const int t    = threadIdx.x;
  const int lane = t & 63;
  const int w    = t >> 6;
  const int cl   = lane & 15;
  const int q    = lane >> 4;
  const int tokbase = blockIdx.x * BM;

  // ---- init small LDS; stage wcomb transposed into bstage head ----
  b1s[t] = b1[t];
#pragma unroll
  for (int i = 0; i < 4; ++i) bes[i][t] = be[i * 256 + t];
  if (t < 4) cnt_s[t] = 0;
  float* wcT = (float*)bstage;           // [4][260] f32 (padded rows)
#pragma unroll
  for (int i = 0; i < 4; ++i) {
    int idx = i * 256 + t;
    wcT[(idx & 3) * 260 + (idx >> 2)] = wcomb[idx];
  }
  __syncthreads();

  // ---- logits = x @ Wcomb + bcomb, fp64 accumulation (flip-proof) ----
  {
    const int tok = t >> 2, e = t & 3;
    const float* xr = x + (size_t)(tokbase + tok) * HD;
    const float* wc = wcT + e * 260;
    double a0 = 0.0, a1 = 0.0, a2 = 0.0, a3 = 0.0;
    for (int k = 0; k < HD; k += 4) {
      f32x4v xv = *(const f32x4v*)(xr + k);
      f32x4v wv = *(const f32x4v*)(wc + k);
      a0 += (double)xv.x * (double)wv.x;
      a1 += (double)xv.y * (double)wv.y;
      a2 += (double)xv.z * (double)wv.z;
      a3 += (double)xv.w * (double)wv.w;
    }
    logits_s[tok][e] = (float)(((a0 + a1) + (a2 + a3)) + (double)bcomb[e]);
  }
  __syncthreads();

  // ---- softmax / argmax / block-local counting sort ----
  if (t < 64) {
    float l0 = logits_s[t][0], l1 = logits_s[t][1];
    float l2 = logits_s[t][2], l3 = logits_s[t][3];
    float m = fmaxf(fmaxf(l0, l1), fmaxf(l2, l3));
    float s = __expf(l0 - m) + __expf(l1 - m) + __expf(l2 - m) + __expf(l3 - m);
    int e = 0; float bl = l0;
    if (l1 > bl) { bl = l1; e = 1; }
    if (l2 > bl) { bl = l2; e = 2; }
    if (l3 > bl) { bl = l3; e = 3; }
    gate_s[t] = 1.0f / s;                 // prob of argmax expert
    eidx_s[t] = e;
    pos_s[t]  = atomicAdd(&cnt_s[e], 1);
  }
  __syncthreads();
  if (t == 0) {
    int b = 0;
#pragma unroll
    for (int e = 0; e < 4; ++e) { base_s[e] = b; b += cnt_s[e]; }
  }
  __syncthreads();
  if (t < 64) perm_s[base_s[eidx_s[t]] + pos_s[t]] = t;
  // (visible after the first barrier in the kc loop below)

  // ---- stage 1: h = x @ W1  (bf16 MFMA, A direct from global) ----
  facc acc1[16];
#pragma unroll
  for (int nt = 0; nt < 16; ++nt) acc1[nt] = (facc){0.f, 0.f, 0.f, 0.f};
  const float* xrow = x + (size_t)(tokbase + w * 16 + cl) * HD;

  for (int kc = 0; kc < 4; ++kc) {
    __syncthreads();                       // prior bstage readers done
    {
      const u16* src = w1t + (size_t)kc * 2048 * 8;
#pragma unroll
      for (int i = 0; i < 8; ++i)
        async16(&bstage[(i * 256 + w * 64) * 8], src + (size_t)(i * 256 + t) * 8);
    }
    __syncthreads();                       // DMA drained (vmcnt 0 at barrier)
#pragma unroll
    for (int h2 = 0; h2 < 2; ++h2) {
      const int k0 = kc * 64 + h2 * 32 + q * 8;
      f32x4v xa = *(const f32x4v*)(xrow + k0);
      f32x4v xb = *(const f32x4v*)(xrow + k0 + 4);
      bfrag a;
      a[0] = (short)f2bf(xa.x); a[1] = (short)f2bf(xa.y);
      a[2] = (short)f2bf(xa.z); a[3] = (short)f2bf(xa.w);
      a[4] = (short)f2bf(xb.x); a[5] = (short)f2bf(xb.y);
      a[6] = (short)f2bf(xb.z); a[7] = (short)f2bf(xb.w);
      const int phys = (h2 * 4 + q) ^ (cl & 7);   // XOR swizzle (2-way max)
#pragma unroll
      for (int nt = 0; nt < 16; ++nt) {
        const int c = nt * 16 + cl;
        bfrag b = *(const bfrag*)&bstage[(c * 8 + phys) * 8];
        acc1[nt] = __builtin_amdgcn_mfma_f32_16x16x32_bf16(a, b, acc1[nt], 0, 0, 0);
      }
    }
  }
  // write h (+b1) to LDS as bf16
#pragma unroll
  for (int nt = 0; nt < 16; ++nt) {
    const int c = nt * 16 + cl;
    const float bb = b1s[c];
#pragma unroll
    for (int r = 0; r < 4; ++r)
      hs[w * 16 + q * 4 + r][c] = f2bf(acc1[nt][r] + bb);
  }
  __syncthreads();

  // ---- stage 2: per-expert grouped GEMM, whole block per 16-row group ----
  for (int e = 0; e < 4; ++e) {
    const int cnt = cnt_s[e];              // block-uniform
    if (cnt == 0) continue;
    const int ng   = (cnt + 15) >> 4;
    const int base = base_s[e];
    facc acc2[4][4];
#pragma unroll
    for (int g = 0; g < 4; ++g)
#pragma unroll
      for (int n4 = 0; n4 < 4; ++n4) acc2[g][n4] = (facc){0.f, 0.f, 0.f, 0.f};

    for (int kc = 0; kc < 4; ++kc) {
      __syncthreads();
      {
        const u16* src = wet + (size_t)(e * 4 + kc) * 2048 * 8;
#pragma unroll
        for (int i = 0; i < 8; ++i)
          async16(&bstage[(i * 256 + w * 64) * 8], src + (size_t)(i * 256 + t) * 8);
      }
      __syncthreads();
#pragma unroll
      for (int g = 0; g < 4; ++g) {
        if (g < ng) {
          const int  rowi  = g * 16 + cl;
          const bool valid = rowi < cnt;
          const int  prow  = perm_s[base + (valid ? rowi : 0)];
#pragma unroll
          for (int h2 = 0; h2 < 2; ++h2) {
            const int k0 = kc * 64 + h2 * 32 + q * 8;
            bfrag a = *(const bfrag*)&hs[prow][k0];
            if (!valid) { bfrag zf = {0,0,0,0,0,0,0,0}; a = zf; }
            const int phys = (h2 * 4 + q) ^ (cl & 7);
#pragma unroll
            for (int n4 = 0; n4 < 4; ++n4) {
              const int c = (w * 4 + n4) * 16 + cl;
              bfrag b = *(const bfrag*)&bstage[(c * 8 + phys) * 8];
              acc2[g][n4] = __builtin_amdgcn_mfma_f32_16x16x32_bf16(a, b, acc2[g][n4], 0, 0, 0);
            }
          }
        }
      }
    }
    // epilogue: out = gate * (acc + be[e])
#pragma unroll
    for (int g = 0; g < 4; ++g) {
      if (g < ng) {
#pragma unroll
        for (int n4 = 0; n4 < 4; ++n4) {
          const int c = (w * 4 + n4) * 16 + cl;
          const float bev = bes[e][c];
#pragma unroll
          for (int r = 0; r < 4; ++r) {
            const int rowi = g * 16 + q * 4 + r;
            if (rowi < cnt) {
              const int tok = perm_s[base + rowi];
              out[(size_t)(tokbase + tok) * HD + c] = gate_s[tok] * (acc2[g][n4][r] + bev);
            }
          }
        }
      }
    }
  }
}

extern "C" void kernel_launch(void* const* d_in, const int* in_sizes, int n_in,
                              void* d_out, int out_size, void* d_ws, size_t ws_size,
                              hipStream_t stream) {
  const float* x  = (const float*)d_in[0];
  const float* W1 = (const float*)d_in[1];
  const float* b1 = (const float*)d_in[2];
  const float* Wg = (const float*)d_in[3];
  const float* We = (const float*)d_in[4];
  const float* be = (const float*)d_in[5];
  float* out = (float*)d_out;

  char* ws = (char*)d_ws;
  u16*   w1t   = (u16*)(ws + WS_W1T);
  u16*   wet   = (u16*)(ws + WS_WET);
  float* wcomb = (float*)(ws + WS_WCOMB);
  float* bcomb = (float*)(ws + WS_BCOMB);

  prep_comb<<<5, 256, 0, stream>>>(W1, b1, Wg, wcomb, bcomb);
  prep_swz <<<160, 256, 0, stream>>>(W1, We, w1t, wet);
  moe_fused<<<NBLK, 256, 0, stream>>>(x, w1t, wet, wcomb, bcomb, b1, be, out);
}